// Round 1
// baseline (568.141 us; speedup 1.0000x reference)
//
#include <hip/hip_runtime.h>
#include <cstdint>
#include <cstddef>

#define ALPHA 0.2f
// N=8192, Fin=512, Fout=256 hard-coded per problem instance.

typedef __attribute__((ext_vector_type(8)))  short short8;   // 8 bf16 (4 VGPRs)
typedef __attribute__((ext_vector_type(16))) float f32x16;   // 32x32 MFMA acc

static __device__ __forceinline__ unsigned short f2bf(float x) {
  union { float f; unsigned u; } c; c.f = x;
  unsigned u = c.u;
  unsigned r = (u + 0x7FFFu + ((u >> 16) & 1u)) >> 16;  // RNE
  return (unsigned short)r;
}
static __device__ __forceinline__ float bf2f(unsigned short b) {
  union { unsigned u; float f; } c; c.u = ((unsigned)b) << 16;
  return c.f;
}

// ---------------- Kernel A: Wh = h @ W  (fp32, 8192x512 * 512x256) ----------
// BM=128, BN=64, BK=32, 256 threads, 8x4 per thread. grid 64*4=256 blocks.
__global__ __launch_bounds__(256, 2) void gemm1(const float* __restrict__ h,
                                                const float* __restrict__ W,
                                                float* __restrict__ Wh) {
  __shared__ float As[32][132];  // [k][m], padded to 132 floats (528B, 16B-mult)
  __shared__ float Bs[32][64];   // [k][n]
  const int t = threadIdx.x;
  const int bid = blockIdx.x;
  const int nb = bid & 3, mb = bid >> 2;
  const int m0 = mb * 128, n0 = nb * 64;
  const int ty = t >> 4, tx = t & 15;   // rows ty*8.., cols tx*4..
  float acc[8][4];
#pragma unroll
  for (int i = 0; i < 8; i++)
#pragma unroll
    for (int j = 0; j < 4; j++) acc[i][j] = 0.f;

  for (int k0 = 0; k0 < 512; k0 += 32) {
#pragma unroll
    for (int c = 0; c < 4; c++) {                 // stage A with transpose
      int m = c * 32 + (t >> 3);
      int kq = (t & 7) * 4;
      float4 v = *(const float4*)&h[(size_t)(m0 + m) * 512 + k0 + kq];
      As[kq + 0][m] = v.x; As[kq + 1][m] = v.y;
      As[kq + 2][m] = v.z; As[kq + 3][m] = v.w;
    }
#pragma unroll
    for (int c = 0; c < 2; c++) {                 // stage B
      int k = c * 16 + (t >> 4);
      int n = (t & 15) * 4;
      *(float4*)&Bs[k][n] = *(const float4*)&W[(size_t)(k0 + k) * 256 + n0 + n];
    }
    __syncthreads();
#pragma unroll
    for (int k = 0; k < 32; k++) {
      float4 a0 = *(float4*)&As[k][ty * 8];
      float4 a1 = *(float4*)&As[k][ty * 8 + 4];
      float4 b  = *(float4*)&Bs[k][tx * 4];
      float av[8] = {a0.x, a0.y, a0.z, a0.w, a1.x, a1.y, a1.z, a1.w};
      float bv[4] = {b.x, b.y, b.z, b.w};
#pragma unroll
      for (int i = 0; i < 8; i++)
#pragma unroll
        for (int j = 0; j < 4; j++) acc[i][j] = fmaf(av[i], bv[j], acc[i][j]);
    }
    __syncthreads();
  }
#pragma unroll
  for (int i = 0; i < 8; i++) {
    float4 v = {acc[i][0], acc[i][1], acc[i][2], acc[i][3]};
    *(float4*)&Wh[(size_t)(m0 + ty * 8 + i) * 256 + n0 + tx * 4] = v;
  }
}

// ------------- Kernel B: per-row f1,f2, u/v pack, and bf16 transpose --------
// one wave per row; grid 2048 x 256
__global__ __launch_bounds__(256) void rowstats(const float* __restrict__ Wh,
                                                const float* __restrict__ a,
                                                float* __restrict__ f1,
                                                float* __restrict__ f2,
                                                unsigned* __restrict__ uvpack,
                                                unsigned short* __restrict__ WhT) {
  const int t = threadIdx.x;
  const int w = t >> 6, lane = t & 63;
  const int i = blockIdx.x * 4 + w;
  float4 wv = *(const float4*)&Wh[(size_t)i * 256 + lane * 4];
  float4 a1 = *(const float4*)&a[lane * 4];
  float4 a2 = *(const float4*)&a[256 + lane * 4];
  float s1 = wv.x * a1.x + wv.y * a1.y + wv.z * a1.z + wv.w * a1.w;
  float s2 = wv.x * a2.x + wv.y * a2.y + wv.z * a2.z + wv.w * a2.w;
#pragma unroll
  for (int off = 32; off; off >>= 1) { s1 += __shfl_xor(s1, off); s2 += __shfl_xor(s2, off); }
  // transposed bf16 copy: WhT[c][i]
  const float wvv[4] = {wv.x, wv.y, wv.z, wv.w};
#pragma unroll
  for (int c = 0; c < 4; c++)
    WhT[(size_t)(lane * 4 + c) * 8192 + i] = f2bf(wvv[c]);
  if (lane == 0) {
    f1[i] = s1; f2[i] = s2;
    float u = __expf(s2), v = __expf(ALPHA * s2);
    uvpack[i] = (unsigned)f2bf(u) | ((unsigned)f2bf(v) << 16);
  }
}

// ---------------- Kernel Bmax: F2max = max_j f2[j] --------------------------
__global__ __launch_bounds__(256) void f2max_k(const float* __restrict__ f2,
                                               float* __restrict__ f2maxp) {
  __shared__ float red[256];
  const int t = threadIdx.x;
  float m = -1e30f;
  for (int c = 0; c < 32; c++) m = fmaxf(m, f2[c * 256 + t]);
  red[t] = m;
  __syncthreads();
  for (int s = 128; s; s >>= 1) {
    if (t < s) red[t] = fmaxf(red[t], red[t + s]);
    __syncthreads();
  }
  if (t == 0) f2maxp[0] = red[0];
}

// ---------------- Kernel C: fused masked-softmax @ Wh (the big one) ---------
// grid 512 = 256 row-blocks (32 rows) x 2 j-halves (4096). 256 threads.
// No online rescaling: M_i = leaky(f1_i + F2max) bounds every logit.
__global__ __launch_bounds__(256, 2) void attn_main(const int* __restrict__ adj,
                                                    const float* __restrict__ f1,
                                                    const unsigned* __restrict__ uvpack,
                                                    const unsigned short* __restrict__ WhT,
                                                    const float* __restrict__ f2maxp,
                                                    float* __restrict__ accP,
                                                    float* __restrict__ lP) {
  __shared__ unsigned uvs[4096];
  __shared__ __align__(16) unsigned short Pt[32][40];  // 80B row stride (16B mult)
  __shared__ float lred[32][8];
  const int t = threadIdx.x;
  const int bid = blockIdx.x;
  const int jh = bid & 1;          // even/odd bids alternate XCD parity -> L2 slice
  const int rb = bid >> 1;
  const int r0 = rb * 32;
  const int jbase = jh * 4096;

#pragma unroll
  for (int c = 0; c < 4; c++) {    // preload u/v for this j-half (16 KB LDS)
    int idx = c * 1024 + t * 4;
    *(uint4*)&uvs[idx] = *(const uint4*)&uvpack[jbase + idx];
  }

  const int r = t >> 3, q = t & 7;           // staging role: row r, j-chunk q
  const float F2max = f2maxp[0];
  const float f1v = f1[r0 + r];
  const float x = f1v + F2max;
  const float M = x > 0.f ? x : ALPHA * x;   // analytic per-row max bound
  const float Ai = __expf(f1v - M);
  const float Bi = __expf(ALPHA * f1v - M);
  const float Ui = __expf(-f1v);             // u_j > Ui  <=>  f1_i + f2_j > 0

  const int lane = t & 63, wave = t >> 6;
  const int am = lane & 31, asel = lane >> 5;
  f32x16 acc0 = {}; f32x16 acc1 = {};
  float lpriv = 0.f;

  const int* adjp = adj + (size_t)(r0 + r) * 8192 + jbase + q * 4;
  const unsigned short* bp0 = WhT + (size_t)(wave * 64 + am) * 8192 + jbase + asel * 8;
  const unsigned short* bp1 = bp0 + (size_t)32 * 8192;

  __syncthreads();

  int4 av = *(const int4*)adjp; adjp += 32;  // software-pipeline the HBM stream
  for (int s = 0; s < 128; s++) {
    int4 avn;
    if (s < 127) { avn = *(const int4*)adjp; }
    adjp += 32;
    uint4 uvq = *(const uint4*)&uvs[s * 32 + q * 4];
    const unsigned uv[4] = {uvq.x, uvq.y, uvq.z, uvq.w};
    const int ad[4] = {av.x, av.y, av.z, av.w};
    float wgt[4];
#pragma unroll
    for (int jj = 0; jj < 4; jj++) {
      float u = bf2f((unsigned short)(uv[jj] & 0xFFFFu));
      float v = bf2f((unsigned short)(uv[jj] >> 16));
      float wv = (u > Ui) ? Ai * u : Bi * v;   // exp(leaky(f1+f2)-M), factorized
      wv = (ad[jj] > 0) ? wv : 0.f;
      wgt[jj] = wv;
    }
    lpriv += (wgt[0] + wgt[1]) + (wgt[2] + wgt[3]);
    unsigned p0 = (unsigned)f2bf(wgt[0]) | ((unsigned)f2bf(wgt[1]) << 16);
    unsigned p1 = (unsigned)f2bf(wgt[2]) | ((unsigned)f2bf(wgt[3]) << 16);
    uint2 pw; pw.x = p0; pw.y = p1;
    *(uint2*)&Pt[r][q * 4] = pw;
    __syncthreads();
#pragma unroll
    for (int hh = 0; hh < 2; hh++) {
      short8 afrag = *(const short8*)&Pt[am][hh * 16 + asel * 8];
      short8 bf0 = *(const short8*)(bp0 + (size_t)s * 32 + hh * 16);
      short8 bf1 = *(const short8*)(bp1 + (size_t)s * 32 + hh * 16);
      acc0 = __builtin_amdgcn_mfma_f32_32x32x16_bf16(afrag, bf0, acc0, 0, 0, 0);
      acc1 = __builtin_amdgcn_mfma_f32_32x32x16_bf16(afrag, bf1, acc1, 0, 0, 0);
    }
    __syncthreads();
    av = avn;
  }

  // store fp32 partials (combine kernel adds the two j-halves; same M_i so no rescale)
  const size_t base = (size_t)jh * (8192 * 256);
#pragma unroll
  for (int reg = 0; reg < 16; reg++) {
    int rowl = (reg & 3) + 8 * (reg >> 2) + 4 * asel;  // verified 32x32 C/D map
    int col = wave * 64 + am;
    accP[base + (size_t)(r0 + rowl) * 256 + col] = acc0[reg];
    accP[base + (size_t)(r0 + rowl) * 256 + col + 32] = acc1[reg];
  }
  lred[r][q] = lpriv;
  __syncthreads();
  if (q == 0) {
    float ssum = 0.f;
#pragma unroll
    for (int k = 0; k < 8; k++) ssum += lred[r][k];
    lP[jh * 8192 + r0 + r] = ssum;
  }
}

// ---------------- Kernel D: combine halves, normalize, ELU ------------------
__global__ __launch_bounds__(256) void combine(const float* __restrict__ accP,
                                               const float* __restrict__ lP,
                                               float* __restrict__ out) {
  const int idx = (blockIdx.x * 256 + threadIdx.x) * 4;
  const int row = idx >> 8;
  float4 a0 = *(const float4*)&accP[idx];
  float4 a1 = *(const float4*)&accP[(size_t)8192 * 256 + idx];
  float l = lP[row] + lP[8192 + row];
  float inv = 1.0f / fmaxf(l, 1e-30f);
  float vv[4] = {(a0.x + a1.x) * inv, (a0.y + a1.y) * inv,
                 (a0.z + a1.z) * inv, (a0.w + a1.w) * inv};
  float4 o;
  o.x = vv[0] > 0.f ? vv[0] : __expf(vv[0]) - 1.f;
  o.y = vv[1] > 0.f ? vv[1] : __expf(vv[1]) - 1.f;
  o.z = vv[2] > 0.f ? vv[2] : __expf(vv[2]) - 1.f;
  o.w = vv[3] > 0.f ? vv[3] : __expf(vv[3]) - 1.f;
  *(float4*)&out[idx] = o;
}

extern "C" void kernel_launch(void* const* d_in, const int* in_sizes, int n_in,
                              void* d_out, int out_size, void* d_ws, size_t ws_size,
                              hipStream_t stream) {
  const float* h  = (const float*)d_in[0];
  const int* adj  = (const int*)d_in[1];
  const float* W  = (const float*)d_in[2];
  const float* a  = (const float*)d_in[3];
  float* out = (float*)d_out;
  char* ws = (char*)d_ws;

  // ws layout (aliased to stay under ~21 MB):
  //  [0, 16M):  Wh fp32 (8 MB, kernels A/B) THEN accP 2x8MB (kernel C onward)
  //  [16M, 20M): WhT bf16 (4 MB)
  //  [20M ...):  f1 (32K), f2 (32K), uvpack (32K), f2max (128B), lP (64K)
  float* Wh            = (float*)ws;
  float* accP          = (float*)ws;
  unsigned short* WhT  = (unsigned short*)(ws + (size_t)(16u << 20));
  float* f1            = (float*)(ws + (size_t)(20u << 20));
  float* f2            = (float*)(ws + (size_t)(20u << 20) + (32u << 10));
  unsigned* uvpack     = (unsigned*)(ws + (size_t)(20u << 20) + (64u << 10));
  float* f2maxp        = (float*)(ws + (size_t)(20u << 20) + (96u << 10));
  float* lP            = (float*)(ws + (size_t)(20u << 20) + (97u << 10));

  gemm1<<<256, 256, 0, stream>>>(h, W, Wh);
  rowstats<<<2048, 256, 0, stream>>>(Wh, a, f1, f2, uvpack, WhT);
  f2max_k<<<1, 256, 0, stream>>>(f2, f2maxp);
  attn_main<<<512, 256, 0, stream>>>(adj, f1, uvpack, WhT, f2maxp, accP, lP);
  combine<<<2048, 256, 0, stream>>>(accP, lP, out);
}